// Round 3
// baseline (273.799 us; speedup 1.0000x reference)
//
#include <hip/hip_runtime.h>

#define NH   12
#define HD   64
#define H    768
#define B_   2
#define S_   2048
#define MTOT (B_*S_)   // 4096
#define KS   1536      // split storage width: [hi(768) | lo(768)]
#define KP   2304      // GEMM k' extent: hi*hi | hi*lo | lo*hi

typedef short bf16x8 __attribute__((ext_vector_type(8)));
typedef float f32x4  __attribute__((ext_vector_type(4)));

#define MFMA(a,b,c) __builtin_amdgcn_mfma_f32_16x16x32_bf16((a),(b),(c),0,0,0)
#define GLL16(g,l) __builtin_amdgcn_global_load_lds( \
    (const __attribute__((address_space(1))) void*)(g), \
    (__attribute__((address_space(3))) void*)(l), 16, 0, 0)

__device__ __forceinline__ unsigned short f2bf(float x){
    union { float f; unsigned u; } c; c.f = x;
    unsigned r = (c.u + 0x7FFFu + ((c.u >> 16) & 1u)) >> 16;   // RNE
    return (unsigned short)r;
}
__device__ __forceinline__ float bf2f(unsigned short b){
    union { unsigned u; float f; } c; c.u = ((unsigned)b) << 16;
    return c.f;
}

// ---------------------------------------------------------------------------
// Split pre-passes: fp32 row [768] -> bf16 [hi(768) | lo(768)]
// ---------------------------------------------------------------------------
__global__ __launch_bounds__(256) void split_x(
    const float* __restrict__ src, unsigned short* __restrict__ dst)
{
    const int m = blockIdx.x;
    const float* s = src + (size_t)m * H;
    unsigned short* d = dst + (size_t)m * KS;
    for (int k = threadIdx.x; k < H; k += 256){
        float v = s[k];
        unsigned short hi = f2bf(v);
        d[k]     = hi;
        d[H + k] = f2bf(v - bf2f(hi));
    }
}

__global__ __launch_bounds__(256) void split_w(
    const float* __restrict__ wq, const float* __restrict__ wk,
    const float* __restrict__ wv, const float* __restrict__ wo,
    unsigned short* __restrict__ Wqkv, unsigned short* __restrict__ Wo_)
{
    const int n = blockIdx.x;      // 0..767
    const int w = blockIdx.y;      // 0..3
    const float* src = (w==0)?wq:(w==1)?wk:(w==2)?wv:wo;
    unsigned short* dst = (w<3) ? &Wqkv[(size_t)(w*768 + n)*KS] : &Wo_[(size_t)n*KS];
    const float* s = src + (size_t)n * H;
    for (int k = threadIdx.x; k < H; k += 256){
        float v = s[k];
        unsigned short hi = f2bf(v);
        dst[k]     = hi;
        dst[H + k] = f2bf(v - bf2f(hi));
    }
}

// ---------------------------------------------------------------------------
// Split-bf16 GEMM: Y[m][n] = sum_k X[m][k]*W[n][k] + bias  (fp32-accurate)
// A = [Xhi|Xlo] (phase seq hi,hi,lo -> ka = k'<768 ? k' : k'-768)
// B = [Whi|Wlo] (phase seq hi,lo,hi -> kb = k'<1536 ? k' : k'-1536)
// 128x128 tile, 4 waves 2x2, BK=32, global_load_lds + XOR chunk swizzle.
// MODE 0: fp32 store + bias.  MODE 1: QKV scatter (Q scaled 1/8, V transposed).
// ---------------------------------------------------------------------------
template<int MODE>
__global__ __launch_bounds__(256) void gemm_split(
    const unsigned short* __restrict__ A, const unsigned short* __restrict__ Bm,
    const float* __restrict__ b0, const float* __restrict__ b1,
    const float* __restrict__ b2,
    float* __restrict__ out,
    unsigned short* __restrict__ Qh, unsigned short* __restrict__ Ql,
    unsigned short* __restrict__ Kh, unsigned short* __restrict__ Kl,
    unsigned short* __restrict__ Vh, unsigned short* __restrict__ Vl)
{
    __shared__ unsigned short As[128*32];
    __shared__ unsigned short Bs[128*32];
    const int tid = threadIdx.x, lane = tid & 63, wave = tid >> 6;
    const int m0 = blockIdx.x*128, n0 = blockIdx.y*128;
    const int wr = wave >> 1, wc = wave & 1;
    const int frow = lane & 15, foct = lane >> 4;
    const int arow = lane >> 2;                        // 16 rows per GLL (64B rows)
    const int achk = ((lane & 3) ^ (arow & 3)) * 8;    // pre-swizzled source chunk
    const int fswz = (foct ^ (frow & 3)) * 8;          // swizzled read chunk

    f32x4 acc[4][4] = {};

    for (int kp = 0; kp < KP; kp += 32){
        const int ka = (kp < 768)  ? kp : kp - 768;
        const int kb = (kp < 1536) ? kp : kp - 1536;
        __syncthreads();
        #pragma unroll
        for (int i = 0; i < 2; ++i){
            const int r0 = (wave*2 + i)*16;
            const int row = r0 + arow;
            GLL16(A  + (size_t)(m0+row)*KS + ka + achk, &As[r0*32]);
            GLL16(Bm + (size_t)(n0+row)*KS + kb + achk, &Bs[r0*32]);
        }
        __syncthreads();
        bf16x8 af[4], bfv[4];
        #pragma unroll
        for (int i = 0; i < 4; ++i)
            af[i]  = *(const bf16x8*)&As[(wr*64 + 16*i + frow)*32 + fswz];
        #pragma unroll
        for (int j = 0; j < 4; ++j)
            bfv[j] = *(const bf16x8*)&Bs[(wc*64 + 16*j + frow)*32 + fswz];
        #pragma unroll
        for (int i = 0; i < 4; ++i)
            #pragma unroll
            for (int j = 0; j < 4; ++j)
                acc[i][j] = MFMA(af[i], bfv[j], acc[i][j]);
    }

    if (MODE == 0){
        #pragma unroll
        for (int i = 0; i < 4; ++i){
            const int m = m0 + wr*64 + 16*i + 4*foct;
            #pragma unroll
            for (int j = 0; j < 4; ++j){
                const int n = n0 + wc*64 + 16*j + frow;
                const float bb = b0[n];
                #pragma unroll
                for (int r = 0; r < 4; ++r)
                    out[(size_t)(m + r)*H + n] = acc[i][j][r] + bb;
            }
        }
    } else {
        const int sect = n0 / 768;                     // 0=Q 1=K 2=V (block-uniform)
        const float* bias = (sect==0) ? b0 : (sect==1) ? b1 : b2;
        const float qs = (sect==0) ? 0.125f : 1.0f;    // fold 1/sqrt(HD) into Q
        unsigned short* Ph = (sect==0) ? Qh : Kh;
        unsigned short* Pl = (sect==0) ? Ql : Kl;
        #pragma unroll
        for (int i = 0; i < 4; ++i){
            const int m  = m0 + wr*64 + 16*i + 4*foct; // rows m..m+3
            const int bb = m >> 11, ss = m & (S_-1);
            #pragma unroll
            for (int j = 0; j < 4; ++j){
                const int nn = (n0 - sect*768) + wc*64 + 16*j + frow;
                const float bv_ = bias[nn];
                const int hh = nn >> 6, dd = nn & 63;
                unsigned short hi[4], lo[4];
                #pragma unroll
                for (int r = 0; r < 4; ++r){
                    float v = (acc[i][j][r] + bv_) * qs;
                    hi[r] = f2bf(v);
                    lo[r] = f2bf(v - bf2f(hi[r]));
                }
                if (sect < 2){                         // [b][h][s][d]
                    const size_t base = ((size_t)(bb*NH + hh)*S_)*HD + dd;
                    #pragma unroll
                    for (int r = 0; r < 4; ++r){
                        Ph[base + (size_t)(ss + r)*HD] = hi[r];
                        Pl[base + (size_t)(ss + r)*HD] = lo[r];
                    }
                } else {                               // V transposed [b][h][d][s]
                    const size_t a = ((size_t)(bb*NH + hh)*HD + dd)*S_ + ss;
                    ushort4 ph; ph.x=hi[0]; ph.y=hi[1]; ph.z=hi[2]; ph.w=hi[3];
                    ushort4 pl; pl.x=lo[0]; pl.y=lo[1]; pl.z=lo[2]; pl.w=lo[3];
                    *(ushort4*)&Vh[a] = ph;
                    *(ushort4*)&Vl[a] = pl;
                }
            }
        }
    }
}

// ---------------------------------------------------------------------------
// Flash attention, MFMA, double-buffered staging (T3-minimum: one barrier per
// tile; __syncthreads' built-in vmcnt(0) drain waits for the prefetch issued
// one full compute-phase earlier). 4 waves; wave w owns q-rows [16w,16w+16).
// K/V staged via global_load_lds with row XOR swizzle. QK^T = 3 mfma (split
// Q,K); PV = 2 mfma (bf16 P, split V). Ps wave-local (no extra barrier).
// LDS = 4*16KB (dbuf K/V hi/lo) + 8KB Ps = 72KB -> 2 blocks/CU.
// ---------------------------------------------------------------------------
__global__ __launch_bounds__(256) void attn_mfma(
    const unsigned short* __restrict__ Qh, const unsigned short* __restrict__ Ql,
    const unsigned short* __restrict__ Kh, const unsigned short* __restrict__ Kl,
    const unsigned short* __restrict__ Vh, const unsigned short* __restrict__ Vl,
    const int* __restrict__ mask, unsigned short* __restrict__ Cs)
{
    __shared__ unsigned short Ksh[2][64*64];
    __shared__ unsigned short Ksl[2][64*64];
    __shared__ unsigned short Vsh[2][64*64];
    __shared__ unsigned short Vsl[2][64*64];
    __shared__ unsigned short Ps[64*64];

    const int tid = threadIdx.x, lane = tid & 63, wave = tid >> 6;
    const int q0 = blockIdx.x*64, h = blockIdx.y, b = blockIdx.z;
    const int frow = lane & 15, foct = lane >> 4;
    const size_t base  = (size_t)(b*NH + h)*S_;   // K rows [s][d]
    const size_t vbase = (size_t)(b*NH + h)*HD;   // V rows [d][s]

    const int srow = lane >> 3;                  // 8 rows per GLL (128B rows)
    const int schk = ((lane & 7) ^ srow) * 8;    // pre-swizzled source chunk
    const int fsw7 = frow & 7;
    const int NT = S_/64;

    // ---- prologue: stage tile 0 into buffer 0 ----
    #pragma unroll
    for (int i = 0; i < 2; ++i){
        const int r0 = (wave*2 + i)*8;
        const int row = r0 + srow;
        const size_t ko = (base + row)*HD + schk;
        GLL16(Kh + ko, &Ksh[0][r0*64]);
        GLL16(Kl + ko, &Ksl[0][r0*64]);
        const size_t vo = (vbase + row)*S_ + schk;
        GLL16(Vh + vo, &Vsh[0][r0*64]);
        GLL16(Vl + vo, &Vsl[0][r0*64]);
    }

    // ---- Q fragments to registers ----
    bf16x8 aqh[2], aql[2];
    {
        const size_t qr = (base + q0 + wave*16 + frow)*HD;
        #pragma unroll
        for (int ks = 0; ks < 2; ++ks){
            aqh[ks] = *(const bf16x8*)&Qh[qr + ks*32 + foct*8];
            aql[ks] = *(const bf16x8*)&Ql[qr + ks*32 + foct*8];
        }
    }

    float mrow[4], lrow[4];
    f32x4 o[4] = {};
    #pragma unroll
    for (int r = 0; r < 4; ++r){ mrow[r] = -1e30f; lrow[r] = 0.f; }

    for (int t = 0; t < NT; ++t){
        const int cur = t & 1;
        __syncthreads();   // drains GLL(t) (vmcnt(0)) + syncs; buf[cur] ready,
                           // all waves done reading buf[cur^1] (tile t-1)

        // ---- prefetch tile t+1 into the other buffer (fully hidden) ----
        if (t + 1 < NT){
            #pragma unroll
            for (int i = 0; i < 2; ++i){
                const int r0 = (wave*2 + i)*8;
                const int row = r0 + srow;
                const size_t ko = (base + (t+1)*64 + row)*HD + schk;
                GLL16(Kh + ko, &Ksh[cur^1][r0*64]);
                GLL16(Kl + ko, &Ksl[cur^1][r0*64]);
                const size_t vo = (vbase + row)*S_ + (t+1)*64 + schk;
                GLL16(Vh + vo, &Vsh[cur^1][r0*64]);
                GLL16(Vl + vo, &Vsl[cur^1][r0*64]);
            }
        }

        // ---- S = (Q/8) K^T ----
        f32x4 sf[4] = {};
        __builtin_amdgcn_s_setprio(1);
        #pragma unroll
        for (int ks = 0; ks < 2; ++ks){
            #pragma unroll
            for (int j = 0; j < 4; ++j){
                const int ad = (16*j + frow)*64 + ((ks*4 + foct) ^ fsw7)*8;
                const bf16x8 kh = *(const bf16x8*)&Ksh[cur][ad];
                const bf16x8 kl = *(const bf16x8*)&Ksl[cur][ad];
                sf[j] = MFMA(aqh[ks], kh, sf[j]);
                sf[j] = MFMA(aqh[ks], kl, sf[j]);
                sf[j] = MFMA(aql[ks], kh, sf[j]);
            }
        }
        __builtin_amdgcn_s_setprio(0);

        #pragma unroll
        for (int j = 0; j < 4; ++j){
            if (mask[b*S_ + t*64 + 16*j + frow] == 0){
                #pragma unroll
                for (int r = 0; r < 4; ++r) sf[j][r] = -1e9f;
            }
        }

        // ---- online softmax (rows 4*foct+r, reduce across the 16 frow lanes) ----
        #pragma unroll
        for (int r = 0; r < 4; ++r){
            float x = fmaxf(fmaxf(sf[0][r], sf[1][r]), fmaxf(sf[2][r], sf[3][r]));
            x = fmaxf(x, __shfl_xor(x, 1));
            x = fmaxf(x, __shfl_xor(x, 2));
            x = fmaxf(x, __shfl_xor(x, 4));
            x = fmaxf(x, __shfl_xor(x, 8));
            const float mnew = fmaxf(mrow[r], x);
            const float sc = __expf(mrow[r] - mnew);
            mrow[r] = mnew;
            float p[4], ps = 0.f;
            #pragma unroll
            for (int j = 0; j < 4; ++j){ p[j] = __expf(sf[j][r] - mnew); ps += p[j]; }
            ps += __shfl_xor(ps, 1);
            ps += __shfl_xor(ps, 2);
            ps += __shfl_xor(ps, 4);
            ps += __shfl_xor(ps, 8);
            lrow[r] = lrow[r]*sc + ps;
            #pragma unroll
            for (int j = 0; j < 4; ++j) o[j][r] *= sc;
            const int prow = wave*16 + 4*foct + r;
            const int psw = (4*foct + r) & 7;
            #pragma unroll
            for (int j = 0; j < 4; ++j){
                const int col = 16*j + frow;
                Ps[prow*64 + ((col >> 3) ^ psw)*8 + (col & 7)] = f2bf(p[j]);
            }
        }

        // ---- O += P V  (P rows are wave-local: no barrier needed) ----
        __builtin_amdgcn_s_setprio(1);
        #pragma unroll
        for (int ks = 0; ks < 2; ++ks){
            const bf16x8 pa = *(const bf16x8*)&Ps[(wave*16 + frow)*64 + ((ks*4 + foct) ^ fsw7)*8];
            #pragma unroll
            for (int j = 0; j < 4; ++j){
                const int ad = (16*j + frow)*64 + ((ks*4 + foct) ^ fsw7)*8;
                o[j] = MFMA(pa, *(const bf16x8*)&Vsh[cur][ad], o[j]);
                o[j] = MFMA(pa, *(const bf16x8*)&Vsl[cur][ad], o[j]);
            }
        }
        __builtin_amdgcn_s_setprio(0);
    }

    // epilogue: normalize, write ctx directly in split form [m][hi|lo]
    #pragma unroll
    for (int r = 0; r < 4; ++r){
        const float inv = 1.0f / lrow[r];
        const int sg = q0 + wave*16 + 4*foct + r;
        const size_t g = (size_t)(b*S_ + sg)*KS;
        #pragma unroll
        for (int j = 0; j < 4; ++j){
            const int col = h*HD + 16*j + frow;
            const float val = o[j][r]*inv;
            const unsigned short hi = f2bf(val);
            Cs[g + col]       = hi;
            Cs[g + 768 + col] = f2bf(val - bf2f(hi));
        }
    }
}

extern "C" void kernel_launch(void* const* d_in, const int* in_sizes, int n_in,
                              void* d_out, int out_size, void* d_ws, size_t ws_size,
                              hipStream_t stream) {
    const float* hs = (const float*)d_in[0];
    const int*  msk = (const int*)  d_in[1];
    const float* wq = (const float*)d_in[2];
    const float* bq = (const float*)d_in[3];
    const float* wk = (const float*)d_in[4];
    const float* bk = (const float*)d_in[5];
    const float* wv = (const float*)d_in[6];
    const float* bv = (const float*)d_in[7];
    const float* wo = (const float*)d_in[8];
    const float* bo = (const float*)d_in[9];
    float* out = (float*)d_out;

    const size_t XS_E   = (size_t)MTOT*KS;        // 6.29M shorts
    const size_t WQKV_E = (size_t)2304*KS;
    const size_t WO_E   = (size_t)768*KS;
    const size_t QKV_E  = (size_t)B_*NH*S_*HD;    // 3.15M shorts

    unsigned short* p = (unsigned short*)d_ws;
    unsigned short* Xs   = p; p += XS_E;          // later reused as Cs
    unsigned short* Wqkv = p; p += WQKV_E;
    unsigned short* Wo_  = p; p += WO_E;
    unsigned short* Qh = p; p += QKV_E;
    unsigned short* Ql = p; p += QKV_E;
    unsigned short* Kh = p; p += QKV_E;
    unsigned short* Kl = p; p += QKV_E;
    unsigned short* Vh = p; p += QKV_E;
    unsigned short* Vl = p; p += QKV_E;
    unsigned short* Cs = Xs;

    split_x<<<dim3(MTOT), 256, 0, stream>>>(hs, Xs);
    split_w<<<dim3(768, 4), 256, 0, stream>>>(wq, wk, wv, wo, Wqkv, Wo_);
    gemm_split<1><<<dim3(MTOT/128, KP/128), 256, 0, stream>>>(
        Xs, Wqkv, bq, bk, bv, nullptr, Qh, Ql, Kh, Kl, Vh, Vl);
    attn_mfma<<<dim3(S_/64, NH, B_), 256, 0, stream>>>(
        Qh, Ql, Kh, Kl, Vh, Vl, msk, Cs);
    gemm_split<0><<<dim3(MTOT/128, H/128), 256, 0, stream>>>(
        Cs, Wo_, bo, nullptr, nullptr, out,
        nullptr, nullptr, nullptr, nullptr, nullptr, nullptr);
}

// Round 4
// 228.473 us; speedup vs baseline: 1.1984x; 1.1984x over previous
//
#include <hip/hip_runtime.h>

#define NH   12
#define HD   64
#define H    768
#define B_   2
#define S_   2048
#define MTOT (B_*S_)   // 4096
#define KS   1536      // split storage width: [hi(768) | lo(768)]
#define KP   2304      // GEMM k' extent: hi*hi | hi*lo | lo*hi

typedef short bf16x8 __attribute__((ext_vector_type(8)));
typedef float f32x4  __attribute__((ext_vector_type(4)));
typedef float f32x16 __attribute__((ext_vector_type(16)));

#define MFMA16(a,b,c) __builtin_amdgcn_mfma_f32_16x16x32_bf16((a),(b),(c),0,0,0)
#define MFMA32(a,b,c) __builtin_amdgcn_mfma_f32_32x32x16_bf16((a),(b),(c),0,0,0)
#define GLL16(g,l) __builtin_amdgcn_global_load_lds( \
    (const __attribute__((address_space(1))) void*)(g), \
    (__attribute__((address_space(3))) void*)(l), 16, 0, 0)

__device__ __forceinline__ unsigned short f2bf(float x){
    union { float f; unsigned u; } c; c.f = x;
    unsigned r = (c.u + 0x7FFFu + ((c.u >> 16) & 1u)) >> 16;   // RNE
    return (unsigned short)r;
}
__device__ __forceinline__ float bf2f(unsigned short b){
    union { unsigned u; float f; } c; c.u = ((unsigned)b) << 16;
    return c.f;
}

// ---------------------------------------------------------------------------
// Split pre-passes: fp32 row [768] -> bf16 [hi(768) | lo(768)]
// ---------------------------------------------------------------------------
__global__ __launch_bounds__(256) void split_x(
    const float* __restrict__ src, unsigned short* __restrict__ dst)
{
    const int m = blockIdx.x;
    const float* s = src + (size_t)m * H;
    unsigned short* d = dst + (size_t)m * KS;
    for (int k = threadIdx.x; k < H; k += 256){
        float v = s[k];
        unsigned short hi = f2bf(v);
        d[k]     = hi;
        d[H + k] = f2bf(v - bf2f(hi));
    }
}

__global__ __launch_bounds__(256) void split_w(
    const float* __restrict__ wq, const float* __restrict__ wk,
    const float* __restrict__ wv, const float* __restrict__ wo,
    unsigned short* __restrict__ Wqkv, unsigned short* __restrict__ Wo_)
{
    const int n = blockIdx.x;      // 0..767
    const int w = blockIdx.y;      // 0..3
    const float* src = (w==0)?wq:(w==1)?wk:(w==2)?wv:wo;
    unsigned short* dst = (w<3) ? &Wqkv[(size_t)(w*768 + n)*KS] : &Wo_[(size_t)n*KS];
    const float* s = src + (size_t)n * H;
    for (int k = threadIdx.x; k < H; k += 256){
        float v = s[k];
        unsigned short hi = f2bf(v);
        dst[k]     = hi;
        dst[H + k] = f2bf(v - bf2f(hi));
    }
}

// ---------------------------------------------------------------------------
// Split-bf16 GEMM (unchanged from r2; proven). 128x128 tile, 4 waves, BK=32.
// ---------------------------------------------------------------------------
template<int MODE>
__global__ __launch_bounds__(256) void gemm_split(
    const unsigned short* __restrict__ A, const unsigned short* __restrict__ Bm,
    const float* __restrict__ b0, const float* __restrict__ b1,
    const float* __restrict__ b2,
    float* __restrict__ out,
    unsigned short* __restrict__ Qh, unsigned short* __restrict__ Ql,
    unsigned short* __restrict__ Kh, unsigned short* __restrict__ Kl,
    unsigned short* __restrict__ Vh, unsigned short* __restrict__ Vl)
{
    __shared__ unsigned short As[128*32];
    __shared__ unsigned short Bs[128*32];
    const int tid = threadIdx.x, lane = tid & 63, wave = tid >> 6;
    const int m0 = blockIdx.x*128, n0 = blockIdx.y*128;
    const int wr = wave >> 1, wc = wave & 1;
    const int frow = lane & 15, foct = lane >> 4;
    const int arow = lane >> 2;
    const int achk = ((lane & 3) ^ (arow & 3)) * 8;
    const int fswz = (foct ^ (frow & 3)) * 8;

    f32x4 acc[4][4] = {};

    for (int kp = 0; kp < KP; kp += 32){
        const int ka = (kp < 768)  ? kp : kp - 768;
        const int kb = (kp < 1536) ? kp : kp - 1536;
        __syncthreads();
        #pragma unroll
        for (int i = 0; i < 2; ++i){
            const int r0 = (wave*2 + i)*16;
            const int row = r0 + arow;
            GLL16(A  + (size_t)(m0+row)*KS + ka + achk, &As[r0*32]);
            GLL16(Bm + (size_t)(n0+row)*KS + kb + achk, &Bs[r0*32]);
        }
        __syncthreads();
        bf16x8 af[4], bfv[4];
        #pragma unroll
        for (int i = 0; i < 4; ++i)
            af[i]  = *(const bf16x8*)&As[(wr*64 + 16*i + frow)*32 + fswz];
        #pragma unroll
        for (int j = 0; j < 4; ++j)
            bfv[j] = *(const bf16x8*)&Bs[(wc*64 + 16*j + frow)*32 + fswz];
        #pragma unroll
        for (int i = 0; i < 4; ++i)
            #pragma unroll
            for (int j = 0; j < 4; ++j)
                acc[i][j] = MFMA16(af[i], bfv[j], acc[i][j]);
    }

    if (MODE == 0){
        #pragma unroll
        for (int i = 0; i < 4; ++i){
            const int m = m0 + wr*64 + 16*i + 4*foct;
            #pragma unroll
            for (int j = 0; j < 4; ++j){
                const int n = n0 + wc*64 + 16*j + frow;
                const float bb = b0[n];
                #pragma unroll
                for (int r = 0; r < 4; ++r)
                    out[(size_t)(m + r)*H + n] = acc[i][j][r] + bb;
            }
        }
    } else {
        const int sect = n0 / 768;
        const float* bias = (sect==0) ? b0 : (sect==1) ? b1 : b2;
        const float qs = (sect==0) ? 0.125f : 1.0f;
        unsigned short* Ph = (sect==0) ? Qh : Kh;
        unsigned short* Pl = (sect==0) ? Ql : Kl;
        #pragma unroll
        for (int i = 0; i < 4; ++i){
            const int m  = m0 + wr*64 + 16*i + 4*foct;
            const int bb = m >> 11, ss = m & (S_-1);
            #pragma unroll
            for (int j = 0; j < 4; ++j){
                const int nn = (n0 - sect*768) + wc*64 + 16*j + frow;
                const float bv_ = bias[nn];
                const int hh = nn >> 6, dd = nn & 63;
                unsigned short hi[4], lo[4];
                #pragma unroll
                for (int r = 0; r < 4; ++r){
                    float v = (acc[i][j][r] + bv_) * qs;
                    hi[r] = f2bf(v);
                    lo[r] = f2bf(v - bf2f(hi[r]));
                }
                if (sect < 2){                         // [b][h][s][d]
                    const size_t base = ((size_t)(bb*NH + hh)*S_)*HD + dd;
                    #pragma unroll
                    for (int r = 0; r < 4; ++r){
                        Ph[base + (size_t)(ss + r)*HD] = hi[r];
                        Pl[base + (size_t)(ss + r)*HD] = lo[r];
                    }
                } else {                               // V transposed [b][h][d][s]
                    const size_t a = ((size_t)(bb*NH + hh)*HD + dd)*S_ + ss;
                    ushort4 ph; ph.x=hi[0]; ph.y=hi[1]; ph.z=hi[2]; ph.w=hi[3];
                    ushort4 pl; pl.x=lo[0]; pl.y=lo[1]; pl.z=lo[2]; pl.w=lo[3];
                    *(ushort4*)&Vh[a] = ph;
                    *(ushort4*)&Vl[a] = pl;
                }
            }
        }
    }
}

// ---------------------------------------------------------------------------
// Flash attention, 32x32x16 MFMA, swapped operands (S^T = mfma(K,Q), O^T =
// mfma(V^T,P^T)). 2 waves x 32 q-rows; KVBLK=64; single-buffer LDS 32KB
// (grid 768 = 3 blocks/CU provides the overlap; r3 showed dbuf's LDS cost
// loses). Each lane owns one q-column: softmax is lane-local + 1 shfl_xor(32).
// P repacked in-register: v_cvt_pk_bf16_f32 + shfl_xor(32)+select (T12-safe).
// Frag layouts: A row=lane&31, k=(lane>>5)*8+e (anchored on r2's verified
// 16x16 pattern); C/D col=lane&31, row=(reg&3)+8*(reg>>2)+4*(lane>>5) [m101].
// ---------------------------------------------------------------------------
__global__ __launch_bounds__(128) void attn_mfma(
    const unsigned short* __restrict__ Qh, const unsigned short* __restrict__ Ql,
    const unsigned short* __restrict__ Kh, const unsigned short* __restrict__ Kl,
    const unsigned short* __restrict__ Vh, const unsigned short* __restrict__ Vl,
    const int* __restrict__ mask, unsigned short* __restrict__ Cs)
{
    __shared__ unsigned short Ksh[64*64], Ksl[64*64], Vsh[64*64], Vsl[64*64];

    const int tid = threadIdx.x, lane = tid & 63, wave = tid >> 6;  // 2 waves
    const int q0 = blockIdx.x*64, h = blockIdx.y, b = blockIdx.z;
    const int l31 = lane & 31, hi = lane >> 5, l7 = lane & 7;
    const size_t base  = (size_t)(b*NH + h)*S_;   // K rows [s][d]
    const size_t vbase = (size_t)(b*NH + h)*HD;   // V rows [d][s]

    const int srow = lane >> 3;                   // 8 rows per GLL (128B rows)
    const int schk = ((lane & 7) ^ srow) * 8;     // pre-swizzled source chunk
    const int NT = S_/64;

    // ---- Q fragments (B-operand: col=lane&31=q, k=(lane>>5)*8+e) ----
    bf16x8 qfh[4], qfl[4];
    {
        const size_t qr = (base + q0 + wave*32 + l31)*HD;
        #pragma unroll
        for (int ds = 0; ds < 4; ++ds){
            qfh[ds] = *(const bf16x8*)&Qh[qr + ds*16 + hi*8];
            qfl[ds] = *(const bf16x8*)&Ql[qr + ds*16 + hi*8];
        }
    }

    float mrow = -1e30f, lrow = 0.f;
    f32x16 o0 = {}, o1 = {};

    for (int t = 0; t < NT; ++t){
        __syncthreads();   // all waves done reading previous tile
        if (wave == 0){    // wave 0 stages K (hi+lo)
            #pragma unroll
            for (int i = 0; i < 8; ++i){
                const int r0 = i*8, row = r0 + srow;
                const size_t off = (base + t*64 + row)*HD + schk;
                GLL16(Kh + off, &Ksh[r0*64]);
                GLL16(Kl + off, &Ksl[r0*64]);
            }
        } else {           // wave 1 stages V^T (hi+lo)
            #pragma unroll
            for (int i = 0; i < 8; ++i){
                const int r0 = i*8, row = r0 + srow;
                const size_t off = (vbase + row)*S_ + t*64 + schk;
                GLL16(Vh + off, &Vsh[r0*64]);
                GLL16(Vl + off, &Vsl[r0*64]);
            }
        }
        __syncthreads();   // implicit vmcnt(0) drain: tiles visible

        // ---- S^T = K (Q/8)^T : 3 split terms, 24 mfma ----
        f32x16 s0 = {}, s1 = {};
        __builtin_amdgcn_s_setprio(1);
        #pragma unroll
        for (int ds = 0; ds < 4; ++ds){
            const int c0 = ((2*ds + hi) ^ l7)*8;
            {
                const int ad = l31*64 + c0;
                const bf16x8 kh0 = *(const bf16x8*)&Ksh[ad];
                const bf16x8 kl0 = *(const bf16x8*)&Ksl[ad];
                s0 = MFMA32(kh0, qfh[ds], s0);
                s0 = MFMA32(kl0, qfh[ds], s0);
                s0 = MFMA32(kh0, qfl[ds], s0);
            }
            {
                const int ad = (32 + l31)*64 + c0;
                const bf16x8 kh1 = *(const bf16x8*)&Ksh[ad];
                const bf16x8 kl1 = *(const bf16x8*)&Ksl[ad];
                s1 = MFMA32(kh1, qfh[ds], s1);
                s1 = MFMA32(kl1, qfh[ds], s1);
                s1 = MFMA32(kh1, qfl[ds], s1);
            }
        }
        __builtin_amdgcn_s_setprio(0);

        // ---- mask (ballot -> 64-bit; all-ones path is a skipped branch) ----
        {
            const unsigned long long mb =
                __ballot(mask[(size_t)b*S_ + t*64 + lane] != 0);
            if (~mb){
                #pragma unroll
                for (int r = 0; r < 16; ++r){
                    const int key = (r&3) + 8*(r>>2) + 4*hi;
                    if (!((mb >> key) & 1))        s0[r] = -1e9f;
                    if (!((mb >> (key + 32)) & 1)) s1[r] = -1e9f;
                }
            }
        }

        // ---- online softmax: lane-local over 32 keys + 1 cross-half shfl ----
        float vmax = -1e30f;
        #pragma unroll
        for (int r = 0; r < 16; ++r) vmax = fmaxf(vmax, fmaxf(s0[r], s1[r]));
        vmax = fmaxf(vmax, __shfl_xor(vmax, 32));
        const float mnew = fmaxf(mrow, vmax);
        const float sc = __expf(mrow - mnew);
        mrow = mnew;
        float ps = 0.f;
        #pragma unroll
        for (int r = 0; r < 16; ++r){
            s0[r] = __expf(s0[r] - mnew);
            s1[r] = __expf(s1[r] - mnew);
            ps += s0[r] + s1[r];
        }
        ps += __shfl_xor(ps, 32);
        lrow = lrow*sc + ps;
        #pragma unroll
        for (int r = 0; r < 16; ++r){ o0[r] *= sc; o1[r] *= sc; }

        // ---- pack P^T to bf16 B-frags in-register (cvt_pk + swap) ----
        // lane(hi=h) holds keys (r&3)+8*(r>>2)+4h; B-frag step s needs keys
        // 16s+8h+{0..7}. Per step: w0..w3 = pk pairs; exchange with lane^32.
        bf16x8 pf[4];
        #pragma unroll
        for (int s = 0; s < 4; ++s){
            const f32x16& pv = (s < 2) ? s0 : s1;
            const int rb = (s & 1)*8;
            unsigned w0, w1, w2, w3;
            asm("v_cvt_pk_bf16_f32 %0, %1, %2" : "=v"(w0) : "v"(pv[rb+0]), "v"(pv[rb+1]));
            asm("v_cvt_pk_bf16_f32 %0, %1, %2" : "=v"(w1) : "v"(pv[rb+2]), "v"(pv[rb+3]));
            asm("v_cvt_pk_bf16_f32 %0, %1, %2" : "=v"(w2) : "v"(pv[rb+4]), "v"(pv[rb+5]));
            asm("v_cvt_pk_bf16_f32 %0, %1, %2" : "=v"(w3) : "v"(pv[rb+6]), "v"(pv[rb+7]));
            const unsigned t0 = (unsigned)__shfl_xor((int)w0, 32);
            const unsigned t1 = (unsigned)__shfl_xor((int)w1, 32);
            const unsigned t2 = (unsigned)__shfl_xor((int)w2, 32);
            const unsigned t3 = (unsigned)__shfl_xor((int)w3, 32);
            union { uint4 u; bf16x8 v; } pk;
            pk.u.x = hi ? t2 : w0;   // keys 8h+{0,1}
            pk.u.y = hi ? t3 : w1;   // keys 8h+{2,3}
            pk.u.z = hi ? w2 : t0;   // keys 8h+{4,5}
            pk.u.w = hi ? w3 : t1;   // keys 8h+{6,7}
            pf[s] = pk.v;
        }

        // ---- O^T += V^T P^T : 16 mfma ----
        __builtin_amdgcn_s_setprio(1);
        #pragma unroll
        for (int s = 0; s < 4; ++s){
            const int c0 = ((2*s + hi) ^ l7)*8;
            const bf16x8 vh0 = *(const bf16x8*)&Vsh[l31*64 + c0];
            const bf16x8 vl0 = *(const bf16x8*)&Vsl[l31*64 + c0];
            o0 = MFMA32(vh0, pf[s], o0);
            o0 = MFMA32(vl0, pf[s], o0);
            const bf16x8 vh1 = *(const bf16x8*)&Vsh[(32 + l31)*64 + c0];
            const bf16x8 vl1 = *(const bf16x8*)&Vsl[(32 + l31)*64 + c0];
            o1 = MFMA32(vh1, pf[s], o1);
            o1 = MFMA32(vl1, pf[s], o1);
        }
        __builtin_amdgcn_s_setprio(0);
    }

    // ---- epilogue: normalize, write ctx split [m][hi|lo] ----
    // lane's q = q0+wave*32+l31; d(reg=a*4+j, dblk) = dblk*32 + 8a + 4hi + j
    const float inv = 1.0f / lrow;
    const int qg = q0 + wave*32 + l31;
    const size_t g = (size_t)(b*S_ + qg)*KS + h*HD;
    #pragma unroll
    for (int dblk = 0; dblk < 2; ++dblk){
        const f32x16& ov = dblk ? o1 : o0;
        #pragma unroll
        for (int a = 0; a < 4; ++a){
            const int d = dblk*32 + 8*a + 4*hi;
            float v0 = ov[a*4+0]*inv, v1 = ov[a*4+1]*inv;
            float v2 = ov[a*4+2]*inv, v3 = ov[a*4+3]*inv;
            ushort4 ph, pl;
            ph.x = f2bf(v0); pl.x = f2bf(v0 - bf2f(ph.x));
            ph.y = f2bf(v1); pl.y = f2bf(v1 - bf2f(ph.y));
            ph.z = f2bf(v2); pl.z = f2bf(v2 - bf2f(ph.z));
            ph.w = f2bf(v3); pl.w = f2bf(v3 - bf2f(ph.w));
            *(ushort4*)&Cs[g + d]       = ph;
            *(ushort4*)&Cs[g + 768 + d] = pl;
        }
    }
}

extern "C" void kernel_launch(void* const* d_in, const int* in_sizes, int n_in,
                              void* d_out, int out_size, void* d_ws, size_t ws_size,
                              hipStream_t stream) {
    const float* hs = (const float*)d_in[0];
    const int*  msk = (const int*)  d_in[1];
    const float* wq = (const float*)d_in[2];
    const float* bq = (const float*)d_in[3];
    const float* wk = (const float*)d_in[4];
    const float* bk = (const float*)d_in[5];
    const float* wv = (const float*)d_in[6];
    const float* bv = (const float*)d_in[7];
    const float* wo = (const float*)d_in[8];
    const float* bo = (const float*)d_in[9];
    float* out = (float*)d_out;

    const size_t XS_E   = (size_t)MTOT*KS;
    const size_t WQKV_E = (size_t)2304*KS;
    const size_t WO_E   = (size_t)768*KS;
    const size_t QKV_E  = (size_t)B_*NH*S_*HD;

    unsigned short* p = (unsigned short*)d_ws;
    unsigned short* Xs   = p; p += XS_E;          // later reused as Cs
    unsigned short* Wqkv = p; p += WQKV_E;
    unsigned short* Wo_  = p; p += WO_E;
    unsigned short* Qh = p; p += QKV_E;
    unsigned short* Ql = p; p += QKV_E;
    unsigned short* Kh = p; p += QKV_E;
    unsigned short* Kl = p; p += QKV_E;
    unsigned short* Vh = p; p += QKV_E;
    unsigned short* Vl = p; p += QKV_E;
    unsigned short* Cs = Xs;

    split_x<<<dim3(MTOT), 256, 0, stream>>>(hs, Xs);
    split_w<<<dim3(768, 4), 256, 0, stream>>>(wq, wk, wv, wo, Wqkv, Wo_);
    gemm_split<1><<<dim3(MTOT/128, KP/128), 256, 0, stream>>>(
        Xs, Wqkv, bq, bk, bv, nullptr, Qh, Ql, Kh, Kl, Vh, Vl);
    attn_mfma<<<dim3(S_/64, NH, B_), 128, 0, stream>>>(
        Qh, Ql, Kh, Kl, Vh, Vl, msk, Cs);
    gemm_split<0><<<dim3(MTOT/128, H/128), 256, 0, stream>>>(
        Cs, Wo_, bo, nullptr, nullptr, out,
        nullptr, nullptr, nullptr, nullptr, nullptr, nullptr);
}